// Round 3
// baseline (579.078 us; speedup 1.0000x reference)
//
#include <hip/hip_runtime.h>
#include <hip/hip_bf16.h>

#define UDIM    256
#define ODIM    128
#define ZDIM    1024
#define NSTEPS  48
#define BM      32
#define THREADS 1024
#define NBLOCKS 128   // 4096 / BM

// ws layout in ushort elements (weights rounded-to-nearest bf16, hi only):
//   KR_hi: [0,       393216)   64 tiles x 12 kc x 64 lanes x 8
//   D_hi : [393216,  425984)   8 tiles x 8 kc x 64 lanes x 8
#define KR_FRAGS 393216
#define D_FRAGS  32768

// sA cols: [0,128)=x, [128,384)=h buf0, [384,640)=h buf1, pad to 664 (16B-aligned rows)
#define SA_W 664

typedef short bf16x8 __attribute__((ext_vector_type(8)));
typedef float f32x4  __attribute__((ext_vector_type(4)));

__device__ __forceinline__ ushort f2bf_bits(float v) {
    __hip_bfloat16 b = __float2bfloat16(v);
    return *reinterpret_cast<ushort*>(&b);
}
__device__ __forceinline__ float bfbits2f(ushort u) {
    __hip_bfloat16 b = *reinterpret_cast<__hip_bfloat16*>(&u);
    return __bfloat162float(b);
}
__device__ __forceinline__ float sigmoid_f(float x) {
    return 1.0f / (1.0f + __expf(-x));
}
__device__ __forceinline__ float tanh_f(float x) {
    return 1.0f - 2.0f / (__expf(2.0f * x) + 1.0f);
}

// ---- prep: pack weights into MFMA B-fragment order, bf16 (round-nearest) ----
__global__ void prep_weights(const float* __restrict__ kernel_w,   // [128,1024]
                             const float* __restrict__ rec_w,      // [256,1024]
                             const float* __restrict__ dense_w,    // [256,128]
                             ushort* __restrict__ ws) {
    int idx = blockIdx.x * blockDim.x + threadIdx.x;
    if (idx < KR_FRAGS) {
        int j  = idx & 7;
        int l  = (idx >> 3) & 63;
        int fc = idx >> 9;          // n*12 + kc
        int kc = fc % 12;
        int n  = fc / 12;
        int k   = kc * 32 + (l >> 4) * 8 + j;
        int col = n * 16 + (l & 15);
        float wv = (k < 128) ? kernel_w[k * ZDIM + col]
                             : rec_w[(k - 128) * ZDIM + col];
        ws[idx] = f2bf_bits(wv);
    } else if (idx < KR_FRAGS + D_FRAGS) {
        int e  = idx - KR_FRAGS;
        int j  = e & 7;
        int l  = (e >> 3) & 63;
        int kc = (e >> 9) & 7;
        int n  = e >> 12;
        int k   = kc * 32 + (l >> 4) * 8 + j;
        int col = n * 16 + (l & 15);
        ws[KR_FRAGS + e] = f2bf_bits(dense_w[k * ODIM + col]);
    }
}

// ---- main: BM=32 persistent LSTM. Each B-fragment feeds 2 row-tiles ----
// (16 MFMA per 4 B-loads per kc: stream latency hidden behind MFMA issue).
// Wave w owns unit-tile j=w: units 16w+cl, n-tiles n = 16g + w, both row-tiles.
__global__ __launch_bounds__(THREADS, 4) void lstm_mfma_kernel(
    const float* __restrict__ last_input,  // [4096,128]
    const float* __restrict__ h0,          // [4096,256]
    const float* __restrict__ c0,          // [4096,256]
    const float* __restrict__ bias,        // [1024]
    const float* __restrict__ dense_b,     // [128]
    const ushort* __restrict__ wsro,
    float* __restrict__ out)               // [4096,48,128]
{
    const ushort* KR = wsro;

    __shared__ ushort sA_hi[BM][SA_W];
    __shared__ ushort sA_lo[BM][SA_W];
    __shared__ __align__(16) ushort sDw[D_FRAGS];

    const int t  = threadIdx.x;
    const int w  = t >> 6;          // wave 0..15
    const int l  = t & 63;
    const int cl = l & 15;          // A row within tile / C col
    const int rg = l >> 4;          // C rows 4*rg..+4, k-group
    const int blockRow = blockIdx.x * BM;

    // ---- stage dense weights into LDS (once) ----
    for (int i = t * 8; i < D_FRAGS; i += THREADS * 8)
        *reinterpret_cast<bf16x8*>(&sDw[i]) =
            *reinterpret_cast<const bf16x8*>(&wsro[KR_FRAGS + i]);

    // ---- stage x0 (cols 0..127) and h0 (buf1: cols 384..639) ----
    for (int i = t; i < BM * ODIM; i += THREADS) {
        int r = i >> 7, c = i & 127;
        float v = last_input[(blockRow + r) * ODIM + c];
        ushort hi = f2bf_bits(v);
        sA_hi[r][c] = hi;
        sA_lo[r][c] = f2bf_bits(v - bfbits2f(hi));
    }
    for (int i = t; i < BM * UDIM; i += THREADS) {
        int r = i >> 8, c = i & 255;
        float v = h0[(blockRow + r) * UDIM + c];
        ushort hi = f2bf_bits(v);
        sA_hi[r][384 + c] = hi;
        sA_lo[r][384 + c] = f2bf_bits(v - bfbits2f(hi));
    }

    // ---- per-lane state: units u = 16*w + cl, rows rt*16 + 4*rg + r ----
    const int unit = 16 * w + cl;
    float cstate[2][4];
    #pragma unroll
    for (int rt = 0; rt < 2; ++rt)
        #pragma unroll
        for (int r = 0; r < 4; ++r)
            cstate[rt][r] = c0[(blockRow + rt * 16 + 4 * rg + r) * UDIM + unit];

    float bz[4];
    #pragma unroll
    for (int g = 0; g < 4; ++g)
        bz[g] = bias[256 * g + unit];

    const int dn = w & 7;           // dense n-tile
    const int drt = w >> 3;         // dense row-tile
    const float db = dense_b[16 * dn + cl];

    // single per-lane KR base offset (ushort elements); per-(g,kc) adds are
    // address arithmetic the compiler folds — no pointer array (VGPR lean).
    const ushort* krbase = KR + (size_t)w * 6144 + (size_t)l * 8;

    __syncthreads();

    for (int s = 0; s < NSTEPS; ++s) {
        const int pw  = s & 1;
        const int hrd = 128 + (pw ^ 1) * 256;   // h read base (prev step)
        const int hwr = 128 + pw * 256;         // h write base (this step)

        // ======== GEMM1: Z[32,1024] = A[32,384] @ KR + bias (hi/lo 2-pass) ========
        f32x4 acc[4][2];
        #pragma unroll
        for (int g = 0; g < 4; ++g) {
            acc[g][0] = (f32x4){bz[g], bz[g], bz[g], bz[g]};
            acc[g][1] = (f32x4){bz[g], bz[g], bz[g], bz[g]};
        }

        #pragma unroll 4
        for (int kc = 0; kc < 12; ++kc) {
            const int koff = (kc < 4) ? (kc * 32 + rg * 8)
                                      : (hrd + (kc - 4) * 32 + rg * 8);
            bf16x8 a0h = *reinterpret_cast<const bf16x8*>(&sA_hi[cl][koff]);
            bf16x8 a0l = *reinterpret_cast<const bf16x8*>(&sA_lo[cl][koff]);
            bf16x8 a1h = *reinterpret_cast<const bf16x8*>(&sA_hi[16 + cl][koff]);
            bf16x8 a1l = *reinterpret_cast<const bf16x8*>(&sA_lo[16 + cl][koff]);
            #pragma unroll
            for (int g = 0; g < 4; ++g) {
                bf16x8 b = *reinterpret_cast<const bf16x8*>(krbase + (size_t)g * 98304 + kc * 512);
                acc[g][0] = __builtin_amdgcn_mfma_f32_16x16x32_bf16(a0h, b, acc[g][0], 0, 0, 0);
                acc[g][0] = __builtin_amdgcn_mfma_f32_16x16x32_bf16(a0l, b, acc[g][0], 0, 0, 0);
                acc[g][1] = __builtin_amdgcn_mfma_f32_16x16x32_bf16(a1h, b, acc[g][1], 0, 0, 0);
                acc[g][1] = __builtin_amdgcn_mfma_f32_16x16x32_bf16(a1l, b, acc[g][1], 0, 0, 0);
            }
        }

        // ======== gates + state update; h_new into the OTHER buffer ========
        // No barrier needed before writes: buffer hwr was last read by
        // GEMM1(s-1), and every wave passed the end-of-step barrier since.
        #pragma unroll
        for (int rt = 0; rt < 2; ++rt) {
            #pragma unroll
            for (int r = 0; r < 4; ++r) {
                float iv = sigmoid_f(acc[0][rt][r]);
                float fv = sigmoid_f(acc[1][rt][r]);
                float gv = tanh_f(acc[2][rt][r]);
                float ov = sigmoid_f(acc[3][rt][r]);
                float cn = fv * cstate[rt][r] + iv * gv;
                cstate[rt][r] = cn;
                float hv = ov * tanh_f(cn);
                ushort hib = f2bf_bits(hv);
                int row = rt * 16 + 4 * rg + r;
                sA_hi[row][hwr + unit] = hib;
                sA_lo[row][hwr + unit] = f2bf_bits(hv - bfbits2f(hib));
            }
        }
        __syncthreads();   // B2: h_new visible (also orders GEMM1 reads vs y-write)

        // ======== dense: Y[32,128] = H[32,256] @ Wd + bd, relu; all 16 waves ========
        {
            f32x4 dacc = (f32x4){db, db, db, db};
            #pragma unroll
            for (int kc = 0; kc < 8; ++kc) {
                const int koff = hwr + kc * 32 + rg * 8;
                bf16x8 ah = *reinterpret_cast<const bf16x8*>(&sA_hi[drt * 16 + cl][koff]);
                bf16x8 al = *reinterpret_cast<const bf16x8*>(&sA_lo[drt * 16 + cl][koff]);
                bf16x8 b  = *reinterpret_cast<const bf16x8*>(&sDw[dn * 4096 + kc * 512 + l * 8]);
                dacc = __builtin_amdgcn_mfma_f32_16x16x32_bf16(ah, b, dacc, 0, 0, 0);
                dacc = __builtin_amdgcn_mfma_f32_16x16x32_bf16(al, b, dacc, 0, 0, 0);
            }
            #pragma unroll
            for (int r = 0; r < 4; ++r) {
                float y = fmaxf(dacc[r], 0.0f);
                int row = drt * 16 + 4 * rg + r;
                out[((size_t)(blockRow + row) * NSTEPS + s) * ODIM + 16 * dn + cl] = y;
                ushort yb = f2bf_bits(y);
                sA_hi[row][16 * dn + cl] = yb;
                sA_lo[row][16 * dn + cl] = f2bf_bits(y - bfbits2f(yb));
            }
        }
        __syncthreads();   // B4: next-step x ready
    }
}

extern "C" void kernel_launch(void* const* d_in, const int* in_sizes, int n_in,
                              void* d_out, int out_size, void* d_ws, size_t ws_size,
                              hipStream_t stream) {
    const float* last_input = (const float*)d_in[0];
    const float* h0         = (const float*)d_in[1];
    const float* c0         = (const float*)d_in[2];
    const float* kernel_w   = (const float*)d_in[3];
    const float* rec_w      = (const float*)d_in[4];
    const float* bias       = (const float*)d_in[5];
    const float* dense_w    = (const float*)d_in[6];
    const float* dense_b    = (const float*)d_in[7];
    float* out  = (float*)d_out;
    ushort* ws  = (ushort*)d_ws;

    const int prep_total = KR_FRAGS + D_FRAGS;
    hipLaunchKernelGGL(prep_weights, dim3((prep_total + 255) / 256), dim3(256), 0, stream,
                       kernel_w, rec_w, dense_w, ws);
    hipLaunchKernelGGL(lstm_mfma_kernel, dim3(NBLOCKS), dim3(THREADS), 0, stream,
                       last_input, h0, c0, bias, dense_b, (const ushort*)ws, out);
}